// Round 4
// baseline (308.063 us; speedup 1.0000x reference)
//
#include <hip/hip_runtime.h>
#include <cstdint>
#include <cstddef>

typedef __bf16 bf16x8 __attribute__((ext_vector_type(8)));
typedef __bf16 bf16x4 __attribute__((ext_vector_type(4)));
typedef short s16x4 __attribute__((ext_vector_type(4)));
typedef float f32x4 __attribute__((ext_vector_type(4)));

__device__ __forceinline__ ushort f2bf(float f) {
  union { float f; uint32_t u; } v; v.f = f;
  uint32_t r = (v.u + 0x7fffu + ((v.u >> 16) & 1u)) >> 16;
  return (ushort)r;
}

__device__ __forceinline__ float fast_exp2(float x) {
#if defined(__HIP_DEVICE_COMPILE__) && __has_builtin(__builtin_amdgcn_exp2f)
  return __builtin_amdgcn_exp2f(x);
#else
  return exp2f(x);
#endif
}

// K=16 bf16 MFMA (C-layout of a 16x16 result feeds directly as B operand).
__device__ __forceinline__ f32x4 mfma16(bf16x4 a, bf16x4 b, f32x4 c) {
#if defined(__HIP_DEVICE_COMPILE__)
#if __has_builtin(__builtin_amdgcn_mfma_f32_16x16x16_bf16)
  return __builtin_amdgcn_mfma_f32_16x16x16_bf16(a, b, c, 0, 0, 0);
#else
  return __builtin_amdgcn_mfma_f32_16x16x16bf16_1k(
      __builtin_bit_cast(s16x4, a), __builtin_bit_cast(s16x4, b), c, 0, 0, 0);
#endif
#else
  (void)a; (void)b;
  return c;  // host stub, never executed
#endif
}

__device__ __forceinline__ void glds16(const ushort* g, ushort* l) {
  __builtin_amdgcn_global_load_lds((const __attribute__((address_space(1))) void*)g,
                                   (__attribute__((address_space(3))) void*)l, 16, 0, 0);
}

// ---------------- fp32 -> bf16 convert (vectorized) ----------------
__global__ void conv_bf16(const float4* __restrict__ in, ushort4* __restrict__ out, int n4) {
  int i = blockIdx.x * blockDim.x + threadIdx.x;
  if (i < n4) {
    float4 v = in[i];
    ushort4 o;
    o.x = f2bf(v.x); o.y = f2bf(v.y); o.z = f2bf(v.z); o.w = f2bf(v.w);
    out[i] = o;
  }
}

// ---------------- fp32 [R][C] -> bf16 [C][R] transpose ----------------
__global__ void transpose_f32_bf16(const float* __restrict__ in, ushort* __restrict__ out,
                                   int R, int C) {
  __shared__ ushort t[32][33];
  int c0 = blockIdx.x * 32, r0 = blockIdx.y * 32;
  int tx = threadIdx.x, ty = threadIdx.y;  // 32 x 8
#pragma unroll
  for (int i = 0; i < 4; ++i)
    t[ty + i * 8][tx] = f2bf(in[(size_t)(r0 + ty + i * 8) * C + c0 + tx]);
  __syncthreads();
#pragma unroll
  for (int i = 0; i < 4; ++i)
    out[(size_t)(c0 + ty + i * 8) * R + r0 + tx] = t[tx][ty + i * 8];
}

// =====================================================================
// QKV projection GEMM: BM=256, BN=128, BK=32, 256 thr (2x2 waves,
// wave tile 128x64, acc = 8x4 f32x4 = 128 regs <- fits 170-cap at
// 3 waves/SIMD with ~40 arch regs; R2's 192-acc variant spilled).
// Grid 24x32 = 768 blocks = EXACTLY 3/CU; LDS 48 KiB dbuf -> 3
// blocks/CU resident, 12 waves/CU.
//
// LDS slot permutation (conflict-free reads + linear DMA dest):
//   unit = 1 KiB sub-block = 16 rows x 4 chunks(16B); slot(r,q) =
//   r*4 + ((q + (r>>1)) & 3) bijects [0,64). DMA dest stays linear
//   (base + lane*16); the SOURCE address encodes the permutation.
//
// Schedule per K-tile t (buf b = t&1), 4 phases:
//   ph0: loadB4 + loadA2(m01); stage ALL of tile t+1 (6 glds16); bar;
//        setprio(1) 8 MFMA setprio(0); bar
//   ph1..ph3: loadA2; bar; 8 MFMA; bar
//   tile end: per-wave vmcnt(0) (t+1 landed, ~3.5 phases of cover); bar
// Counted-wait: vmcnt never drained mid-tile (T4).
// =====================================================================
#define BAR8() do { asm volatile("" ::: "memory"); \
                    __builtin_amdgcn_s_barrier();  \
                    asm volatile("" ::: "memory"); } while (0)
#define VMC0()  asm volatile("s_waitcnt vmcnt(0)" ::: "memory")

__launch_bounds__(256, 3)
__global__ void gemm8_qkv(const ushort* __restrict__ A, const ushort* __restrict__ Bt,
                          const float* __restrict__ bias,
                          ushort* __restrict__ o0, ushort* __restrict__ o1,
                          ushort* __restrict__ o2) {
  constexpr int K = 1024;
  constexpr int NT = 32;  // K / 32
  __shared__ ushort smem[24576];  // 48 KiB: A [0,16384), B [16384,24576)

  const int tid = threadIdx.x;
  const int wid = tid >> 6;
  const int lane = tid & 63;
  const int quad = lane >> 4;
  const int l16 = lane & 15;
  const int wr = wid >> 1;  // 0..1: row half (128 rows each)
  const int wc = wid & 1;   // 0..1: col half (64 cols each)

  // XCD-aware bijective swizzle: 768 blocks = 8 XCDs x 96 contiguous
  int wg = blockIdx.y * gridDim.x + blockIdx.x;
  wg = (wg & 7) * 96 + (wg >> 3);
  const int m0 = (wg / 24) * 256;   // 32 M-tiles
  const int n0 = (wg % 24) * 128;   // 24 N-tiles

  // ---- staging addressing (slot-permuted source, linear dest) ----
  const int r_l = lane >> 2;                      // row within 16-row sub-block
  const int q_l = ((lane & 3) - (r_l >> 1)) & 3;  // k-chunk this lane sources
  // A: wave stages rows wid*64 .. +63 (4 sub-blocks)
  const ushort* gA0 = A + (size_t)(m0 + wid * 64 + r_l) * K + q_l * 8;
  // B: wave stages rows wid*32 .. +31 (2 sub-blocks)
  const ushort* gB0 = Bt + (size_t)(n0 + wid * 32 + r_l) * K + q_l * 8;
  ushort* dA0 = smem + wid * 2048 + lane * 8;
  ushort* dB0 = smem + 16384 + wid * 1024 + lane * 8;

  auto stageAll = [&](int t1, int bs) {
    const ushort* sa = gA0 + t1 * 32;
    ushort* da = dA0 + bs * 8192;
#pragma unroll
    for (int u = 0; u < 4; ++u) glds16(sa + u * 16 * K, da + u * 512);
    const ushort* sb = gB0 + t1 * 32;
    ushort* db = dB0 + bs * 4096;
#pragma unroll
    for (int u = 0; u < 2; ++u) glds16(sb + u * 16 * K, db + u * 512);
  };

  // ---- fragment read addressing ----
  const int slot8 = (l16 * 4 + ((quad + (l16 >> 1)) & 3)) * 8;

  f32x4 acc[8][4];
#pragma unroll
  for (int i = 0; i < 8; ++i)
#pragma unroll
    for (int j = 0; j < 4; ++j) acc[i][j] = (f32x4){0.f, 0.f, 0.f, 0.f};
  bf16x8 aFr[2], bFr[4];

  auto loadB4 = [&](int b) {
#pragma unroll
    for (int n = 0; n < 4; ++n)
      bFr[n] = *(const bf16x8*)(smem + 16384 + b * 4096 + (wc * 4 + n) * 512 + slot8);
  };
  auto loadA2 = [&](int b, int mp) {
#pragma unroll
    for (int m = 0; m < 2; ++m)
      aFr[m] = *(const bf16x8*)(smem + b * 8192 + (wr * 8 + mp * 2 + m) * 512 + slot8);
  };
  auto mma8 = [&](int mp) {
    __builtin_amdgcn_s_setprio(1);
#pragma unroll
    for (int m = 0; m < 2; ++m)
#pragma unroll
      for (int n = 0; n < 4; ++n)
        acc[mp * 2 + m][n] = __builtin_amdgcn_mfma_f32_16x16x32_bf16(
            aFr[m], bFr[n], acc[mp * 2 + m][n], 0, 0, 0);
    __builtin_amdgcn_s_setprio(0);
  };

  // ---- prologue ----
  stageAll(0, 0);
  VMC0();
  BAR8();

#pragma unroll 2
  for (int t = 0; t < NT; ++t) {
    const int b = t & 1;
    // phase 0: m-frags 0,1 x 4 n-frags; prefetch whole tile t+1
    loadB4(b);
    loadA2(b, 0);
    if (t + 1 < NT) stageAll(t + 1, b ^ 1);
    BAR8();
    mma8(0);
    BAR8();
    // phase 1
    loadA2(b, 1);
    BAR8();
    mma8(1);
    BAR8();
    // phase 2
    loadA2(b, 2);
    BAR8();
    mma8(2);
    BAR8();
    // phase 3
    loadA2(b, 3);
    BAR8();
    mma8(3);
    if (t + 1 < NT) VMC0();   // tile t+1 landed (issued ~3.5 phases ago)
    BAR8();
  }

  // ---- epilogue: 2 per-chunk passes (each 64 cols = one head, aligned) ----
  // Q/K chunk staged as [256 rows][64 cols], phys chunk = (dloc>>3)^(R&7).
  // V chunk staged transposed [64 d][256 s] (layouts HW-verified in R2).
  const int bb = m0 >> 11;
  const int s0 = m0 & 2047;

#pragma unroll
  for (int hc = 0; hc < 2; ++hc) {
    const int gc0 = n0 + hc * 64;
    const int sel = gc0 >> 10;               // 0=Q 1=K 2=V (chunk head-aligned)
    const int head = (gc0 & 1023) >> 6;
    const size_t bh = (size_t)(bb * 16 + head);
    if (hc) __syncthreads();                 // prior pass reads done
    // write this chunk's acc frags into smem (waves with wc==hc own it)
    if (wc == hc) {
#pragma unroll
      for (int j = 0; j < 4; ++j) {
        const int dloc = j * 16 + l16;       // 0..63
        const float bv = bias[gc0 + dloc];
#pragma unroll
        for (int i = 0; i < 8; ++i) {
#pragma unroll
          for (int r = 0; r < 4; ++r) {
            const int R = wr * 128 + i * 16 + quad * 4 + r;  // 0..255
            float v = acc[i][j][r] + bv;
            if (sel == 0) v *= 0.18033688011112042f;  // (1/8)*log2(e)
            const ushort u = f2bf(v);
            if (sel == 2) {
              const int lc = R >> 3;
              const int key = ((dloc & 1) << 2) | (lc >> 3);
              const int phys = (lc & 24) | ((lc ^ key) & 7);
              smem[dloc * 256 + phys * 8 + (R & 7)] = u;
            } else {
              smem[R * 64 + (((dloc >> 3) ^ (R & 7)) << 3) + (dloc & 7)] = u;
            }
          }
        }
      }
    }
    __syncthreads();
    // coalesced read-out: 128B per thread
    if (sel != 2) {
      ushort* o = sel ? o1 : o0;
      const int R = tid;                     // 0..255
      ushort* dst = o + (bh * 2048 + s0 + R) * 64;
      const int key = R & 7;
      const uint4* srow = (const uint4*)(smem + R * 64);
#pragma unroll
      for (int g = 0; g < 8; ++g)
        ((uint4*)dst)[g] = srow[g ^ key];
    } else {
      const int d = tid >> 2;                // 0..63
      const int sq = tid & 3;                // s-quarter
      ushort* dst = o2 + (((size_t)(bh * 32 + (s0 >> 6) + sq)) << 12) + d * 64;
      const uint4* srow = (const uint4*)(smem + d * 256);
#pragma unroll
      for (int g = 0; g < 8; ++g) {
        const int lc = sq * 8 + g;
        const int key = ((d & 1) << 2) | sq;
        const int phys = (lc & 24) | ((lc ^ key) & 7);
        ((uint4*)dst)[g] = srow[phys];
      }
    }
  }
}

// ---------------- bf16 GEMM: C = A[M][K] @ Bt[N][K]^T + bias ----------------
// (retained for the output projection, MODE 1: fp32 out[row*N+col] direct)
template <int MODE>
__launch_bounds__(256)
__global__ void gemm_bt(const ushort* __restrict__ A, const ushort* __restrict__ Bt,
                        const float* __restrict__ bias,
                        ushort* __restrict__ o0, ushort* __restrict__ o1,
                        ushort* __restrict__ o2, float* __restrict__ of,
                        int M, int N, int K) {
  __shared__ ushort As[128 * 32];
  __shared__ ushort Bs[128 * 32];
  __shared__ ushort Ts[MODE == 0 ? 4 * 64 * 68 : 4];
  const int tid = threadIdx.x;
  const int wid = tid >> 6;
  const int lane = tid & 63;
  const int quad = lane >> 4;
  const int l16 = lane & 15;
  const int m0 = blockIdx.y * 128;
  const int n0 = blockIdx.x * 128;
  const int wm = (wid >> 1) * 64;
  const int wn = (wid & 1) * 64;
  const int srow = lane >> 2;
  const int scol = (lane & 3) << 3;

  f32x4 acc[4][4];
#pragma unroll
  for (int i = 0; i < 4; ++i)
#pragma unroll
    for (int j = 0; j < 4; ++j) acc[i][j] = (f32x4){0.f, 0.f, 0.f, 0.f};

  const int c0 = wid * 2, c1 = wid * 2 + 1;
  const ushort* gA0 = A + (size_t)(m0 + c0 * 16 + srow) * K + scol;
  const ushort* gA1 = A + (size_t)(m0 + c1 * 16 + srow) * K + scol;
  const ushort* gB0 = Bt + (size_t)(n0 + c0 * 16 + srow) * K + scol;
  const ushort* gB1 = Bt + (size_t)(n0 + c1 * 16 + srow) * K + scol;
  ushort* lA0 = As + c0 * 512 + lane * 8;
  ushort* lA1 = As + c1 * 512 + lane * 8;
  ushort* lB0 = Bs + c0 * 512 + lane * 8;
  ushort* lB1 = Bs + c1 * 512 + lane * 8;

  for (int k0 = 0; k0 < K; k0 += 32) {
    __syncthreads();
    glds16(gA0 + k0, lA0);
    glds16(gA1 + k0, lA1);
    glds16(gB0 + k0, lB0);
    glds16(gB1 + k0, lB1);
    __syncthreads();
    bf16x8 af[4], bfr[4];
#pragma unroll
    for (int i = 0; i < 4; ++i)
      af[i] = *(const bf16x8*)(As + (wm + i * 16 + l16) * 32 + quad * 8);
#pragma unroll
    for (int j = 0; j < 4; ++j)
      bfr[j] = *(const bf16x8*)(Bs + (wn + j * 16 + l16) * 32 + quad * 8);
#pragma unroll
    for (int i = 0; i < 4; ++i)
#pragma unroll
      for (int j = 0; j < 4; ++j)
        acc[i][j] = __builtin_amdgcn_mfma_f32_16x16x32_bf16(af[i], bfr[j], acc[i][j], 0, 0, 0);
  }

  if (MODE == 1) {
#pragma unroll
    for (int i = 0; i < 4; ++i)
#pragma unroll
      for (int j = 0; j < 4; ++j) {
        const int col = n0 + wn + j * 16 + l16;
        const float bv = bias[col];
#pragma unroll
        for (int r = 0; r < 4; ++r) {
          const int row = m0 + wm + i * 16 + quad * 4 + r;
          of[(size_t)row * N + col] = acc[i][j][r] + bv;
        }
      }
  } else {
    ushort* T = &Ts[wid * (64 * 68)];
    const int col0 = n0 + wn;
    const int sel = col0 >> 10;
    const int hh = (col0 & 1023) >> 6;
    const int row0 = m0 + wm;
    const int bb = row0 >> 11;
    const int s0 = row0 & 2047;
    const size_t bh = (size_t)(bb * 16 + hh);
#pragma unroll
    for (int j = 0; j < 4; ++j) {
      const float bv = bias[col0 + j * 16 + l16];
      const int dl = j * 16 + l16;
#pragma unroll
      for (int i = 0; i < 4; ++i) {
#pragma unroll
        for (int r = 0; r < 4; ++r) {
          const int sl = i * 16 + quad * 4 + r;
          float v = acc[i][j][r] + bv;
          if (sel == 0) v *= 0.18033688011112042f;
          const ushort u = f2bf(v);
          if (sel == 2) T[dl * 68 + sl] = u;
          else          T[sl * 68 + dl] = u;
        }
      }
    }
    asm volatile("s_waitcnt lgkmcnt(0)" ::: "memory");
    ushort* dst;
    if (sel == 2) dst = o2 + ((bh * 32 + (s0 >> 6)) << 12) + lane * 64;
    else          dst = (sel == 0 ? o0 : o1) + (bh * 2048 + s0 + lane) * 64;
    const ushort* Trow = &T[lane * 68];
#pragma unroll
    for (int k = 0; k < 16; ++k)
      *(ushort4*)(dst + k * 4) = *(const ushort4*)(Trow + k * 4);
  }
}

// ---------------- flash attention (causal) ----------------
__launch_bounds__(256)
__global__ void attn_fused(const ushort* __restrict__ Qb, const ushort* __restrict__ Kb,
                           const ushort* __restrict__ Vt, ushort* __restrict__ Ob) {
  const int bh = blockIdx.y;
  const int pair = blockIdx.x;
  const int tid = threadIdx.x;
  const int wid = tid >> 6;
  const int lane = tid & 63;
  const int quad = lane >> 4;
  const int l16 = lane & 15;

  __shared__ ushort Ks[2][2][64 * 32];
  __shared__ ushort Vs[2][2][64 * 32];

  const int lr = lane >> 2;
  const int jphys = lane & 3;
  const int skey = (lr >> 1) & 3;
  const int jlog = jphys ^ skey;
  const int srow = wid * 16 + lr;
  const ushort* KgL = Kb + (size_t)bh * 2048 * 64 + (size_t)srow * 64 + jlog * 8;
  const ushort* VgL = Vt + (size_t)bh * 32 * 4096 + (size_t)srow * 64 + jlog * 8;
  ushort* ldsK0[2], *ldsK1[2], *ldsV0[2], *ldsV1[2];
#pragma unroll
  for (int buf = 0; buf < 2; ++buf) {
    ldsK0[buf] = &Ks[buf][0][wid * 16 * 32] + lane * 8;
    ldsK1[buf] = &Ks[buf][1][wid * 16 * 32] + lane * 8;
    ldsV0[buf] = &Vs[buf][0][wid * 16 * 32] + lane * 8;
    ldsV1[buf] = &Vs[buf][1][wid * 16 * 32] + lane * 8;
  }
  auto stage = [&](int jt) {
    const int buf = jt & 1;
    const ushort* ks = KgL + (size_t)jt * 4096;
    const ushort* vs = VgL + (size_t)jt * 4096;
    glds16(ks, ldsK0[buf]);
    glds16(ks + 32, ldsK1[buf]);
    glds16(vs, ldsV0[buf]);
    glds16(vs + 32, ldsV1[buf]);
  };

  const int rkey = (l16 >> 1) & 3;
  const int b = bh >> 4, h = bh & 15;

  auto process = [&](int qt) {
    const int qg0 = qt * 128 + wid * 32;

    const ushort* Qg = Qb + ((size_t)bh * 2048 + qg0) * 64;
    bf16x8 qa[2][2];
#pragma unroll
    for (int f = 0; f < 2; ++f)
#pragma unroll
      for (int hh = 0; hh < 2; ++hh)
        qa[f][hh] = *(const bf16x8*)(Qg + (f * 16 + l16) * 64 + hh * 32 + quad * 8);

    f32x4 o[2][4];
    float rs[2];
#pragma unroll
    for (int f = 0; f < 2; ++f) {
      rs[f] = 0.f;
#pragma unroll
      for (int m = 0; m < 4; ++m) o[f][m] = (f32x4){0.f, 0.f, 0.f, 0.f};
    }

    const int nIt = 2 * qt + 2;
    stage(0);

    for (int jt = 0; jt < nIt; ++jt) {
      __syncthreads();
      if (jt + 1 < nIt) stage(jt + 1);

      const int kvb = jt * 64;
      if (kvb > qg0 + 31) continue;
      const int buf = jt & 1;

      f32x4 s[2][4];
#pragma unroll
      for (int n = 0; n < 4; ++n) {
        const int koff = (n * 16 + l16) * 32 + (quad ^ rkey) * 8;
        bf16x8 kb0 = *(const bf16x8*)&Ks[buf][0][koff];
        bf16x8 kb1 = *(const bf16x8*)&Ks[buf][1][koff];
#pragma unroll
        for (int f = 0; f < 2; ++f) {
          f32x4 z = (f32x4){0.f, 0.f, 0.f, 0.f};
          z = __builtin_amdgcn_mfma_f32_16x16x32_bf16(kb0, qa[f][0], z, 0, 0, 0);
          z = __builtin_amdgcn_mfma_f32_16x16x32_bf16(kb1, qa[f][1], z, 0, 0, 0);
          s[f][n] = z;
        }
      }

      bf16x4 p[2][4];
      if (kvb + 63 <= qg0) {
#pragma unroll
        for (int f = 0; f < 2; ++f)
#pragma unroll
          for (int n = 0; n < 4; ++n) {
            float pe[4];
#pragma unroll
            for (int r = 0; r < 4; ++r) {
              pe[r] = fast_exp2(s[f][n][r]);
              rs[f] += pe[r];
            }
            p[f][n] = (bf16x4){(__bf16)pe[0], (__bf16)pe[1], (__bf16)pe[2], (__bf16)pe[3]};
          }
      } else {
#pragma unroll
        for (int f = 0; f < 2; ++f) {
          const int qg = qg0 + f * 16 + l16;
#pragma unroll
          for (int n = 0; n < 4; ++n) {
            const int kg0 = kvb + n * 16 + quad * 4;
            float pe[4];
#pragma unroll
            for (int r = 0; r < 4; ++r) {
              float e = fast_exp2(s[f][n][r]);
              pe[r] = (kg0 + r > qg) ? 0.f : e;
              rs[f] += pe[r];
            }
            p[f][n] = (bf16x4){(__bf16)pe[0], (__bf16)pe[1], (__bf16)pe[2], (__bf16)pe[3]};
          }
        }
      }

#pragma unroll
      for (int m = 0; m < 4; ++m) {
        const int vrow = (m * 16 + l16) * 32;
#pragma unroll
        for (int n = 0; n < 4; ++n) {
          const int clog = (n & 1) * 2 + (quad >> 1);
          const int voff = vrow + (clog ^ rkey) * 8 + (quad & 1) * 4;
          bf16x4 va = *(const bf16x4*)&Vs[buf][n >> 1][voff];
#pragma unroll
          for (int f = 0; f < 2; ++f) o[f][m] = mfma16(va, p[f][n], o[f][m]);
        }
      }
    }

#pragma unroll
    for (int f = 0; f < 2; ++f) {
      float t = rs[f];
      t += __shfl_xor(t, 16, 64);
      t += __shfl_xor(t, 32, 64);
      const float il = 1.f / t;
      const int q = qg0 + f * 16 + l16;
      ushort* dst = Ob + ((size_t)b * 2048 + q) * 1024 + h * 64;
#pragma unroll
      for (int m = 0; m < 4; ++m) {
        ushort4 w;
        w.x = f2bf(o[f][m][0] * il);
        w.y = f2bf(o[f][m][1] * il);
        w.z = f2bf(o[f][m][2] * il);
        w.w = f2bf(o[f][m][3] * il);
        *(ushort4*)(dst + m * 16 + quad * 4) = w;
      }
    }
  };

  process(15 - pair);
  __syncthreads();
  process(pair);
}

// ---------------- launch ----------------
extern "C" void kernel_launch(void* const* d_in, const int* in_sizes, int n_in,
                              void* d_out, int out_size, void* d_ws, size_t ws_size,
                              hipStream_t stream) {
  const float* x    = (const float*)d_in[0];  // [4,2048,1024]
  const float* Wqkv = (const float*)d_in[1];  // [1024,3072]
  const float* bqkv = (const float*)d_in[2];  // [3072]
  const float* Wo   = (const float*)d_in[3];  // [1024,1024]
  const float* bo   = (const float*)d_in[4];  // [1024]
  float* out = (float*)d_out;                 // [4,2048,1024] fp32

  char* ws = (char*)d_ws;
  size_t off = 0;
  auto alloc = [&](size_t bytes) {
    void* p = ws + off;
    off += (bytes + 255) & ~(size_t)255;
    return p;
  };
  ushort* xbf    = (ushort*)alloc((size_t)8192 * 1024 * 2);
  ushort* Wqkv_t = (ushort*)alloc((size_t)3072 * 1024 * 2);
  ushort* Wo_t   = (ushort*)alloc((size_t)1024 * 1024 * 2);
  ushort* Qb     = (ushort*)alloc((size_t)64 * 2048 * 64 * 2);
  ushort* Kb     = (ushort*)alloc((size_t)64 * 2048 * 64 * 2);
  ushort* Vb     = (ushort*)alloc((size_t)64 * 2048 * 64 * 2);  // tiled V^T
  ushort* Ab     = (ushort*)alloc((size_t)8192 * 1024 * 2);

  // 1. x -> bf16
  conv_bf16<<<dim3(8192), dim3(256), 0, stream>>>((const float4*)x, (ushort4*)xbf,
                                                  8192 * 1024 / 4);
  // 2. transpose weights -> bf16 [N][K]
  transpose_f32_bf16<<<dim3(96, 32), dim3(32, 8), 0, stream>>>(Wqkv, Wqkv_t, 1024, 3072);
  transpose_f32_bf16<<<dim3(32, 32), dim3(32, 8), 0, stream>>>(Wo, Wo_t, 1024, 1024);
  // 3. QKV projection: 256x128 tiles, 768 blocks = exactly 3/CU residency
  gemm8_qkv<<<dim3(24, 32), dim3(256), 0, stream>>>(xbf, Wqkv_t, bqkv, Qb, Kb, Vb);
  // 4. causal flash attention (paired q-tiles: 512 uniform blocks)
  attn_fused<<<dim3(8, 64), dim3(256), 0, stream>>>(Qb, Kb, Vb, Ab);
  // 5. output projection
  gemm_bt<1><<<dim3(8, 64), dim3(256), 0, stream>>>(Ab, Wo_t, bo, nullptr, nullptr, nullptr,
                                                    out, 8192, 1024, 1024);
}

// Round 5
// 259.669 us; speedup vs baseline: 1.1864x; 1.1864x over previous
//
#include <hip/hip_runtime.h>
#include <cstdint>
#include <cstddef>

typedef __bf16 bf16x8 __attribute__((ext_vector_type(8)));
typedef __bf16 bf16x4 __attribute__((ext_vector_type(4)));
typedef short s16x4 __attribute__((ext_vector_type(4)));
typedef float f32x4 __attribute__((ext_vector_type(4)));

__device__ __forceinline__ ushort f2bf(float f) {
  union { float f; uint32_t u; } v; v.f = f;
  uint32_t r = (v.u + 0x7fffu + ((v.u >> 16) & 1u)) >> 16;
  return (ushort)r;
}

__device__ __forceinline__ float fast_exp2(float x) {
#if defined(__HIP_DEVICE_COMPILE__) && __has_builtin(__builtin_amdgcn_exp2f)
  return __builtin_amdgcn_exp2f(x);
#else
  return exp2f(x);
#endif
}

// K=16 bf16 MFMA (C-layout of a 16x16 result feeds directly as B operand).
__device__ __forceinline__ f32x4 mfma16(bf16x4 a, bf16x4 b, f32x4 c) {
#if defined(__HIP_DEVICE_COMPILE__)
#if __has_builtin(__builtin_amdgcn_mfma_f32_16x16x16_bf16)
  return __builtin_amdgcn_mfma_f32_16x16x16_bf16(a, b, c, 0, 0, 0);
#else
  return __builtin_amdgcn_mfma_f32_16x16x16bf16_1k(
      __builtin_bit_cast(s16x4, a), __builtin_bit_cast(s16x4, b), c, 0, 0, 0);
#endif
#else
  (void)a; (void)b;
  return c;  // host stub, never executed
#endif
}

__device__ __forceinline__ void glds16(const ushort* g, ushort* l) {
  __builtin_amdgcn_global_load_lds((const __attribute__((address_space(1))) void*)g,
                                   (__attribute__((address_space(3))) void*)l, 16, 0, 0);
}

// ---------------- fp32 -> bf16 convert (vectorized) ----------------
__global__ void conv_bf16(const float4* __restrict__ in, ushort4* __restrict__ out, int n4) {
  int i = blockIdx.x * blockDim.x + threadIdx.x;
  if (i < n4) {
    float4 v = in[i];
    ushort4 o;
    o.x = f2bf(v.x); o.y = f2bf(v.y); o.z = f2bf(v.z); o.w = f2bf(v.w);
    out[i] = o;
  }
}

// ---------------- fp32 [R][C] -> bf16 [C][R] transpose ----------------
__global__ void transpose_f32_bf16(const float* __restrict__ in, ushort* __restrict__ out,
                                   int R, int C) {
  __shared__ ushort t[32][33];
  int c0 = blockIdx.x * 32, r0 = blockIdx.y * 32;
  int tx = threadIdx.x, ty = threadIdx.y;  // 32 x 8
#pragma unroll
  for (int i = 0; i < 4; ++i)
    t[ty + i * 8][tx] = f2bf(in[(size_t)(r0 + ty + i * 8) * C + c0 + tx]);
  __syncthreads();
#pragma unroll
  for (int i = 0; i < 4; ++i)
    out[(size_t)(c0 + ty + i * 8) * R + r0 + tx] = t[tx][ty + i * 8];
}

// =====================================================================
// Triple-buffered bf16 GEMM, baseline geometry (proven spill-free):
// 128x128 tile, BK=32, 4 waves of 64x64 (acc = 4x4 f32x4 = 64 regs,
// ~140 total <= 170 cap at 3 waves/SIMD). LDS = 3 bufs x (A 8KB + B 8KB)
// = 48 KiB -> 3 blocks/CU; grid 1536 (MODE 0) = 2 exact rounds.
//
// vs baseline gemm_bt (92.5us, MfmaUtil 23%):
//  - ONE raw barrier + counted s_waitcnt vmcnt(4) per K-step (T4):
//    stage(t+2) issued at iter t, waited at end of iter t+1 -> a full
//    iteration of cover; loads stay in flight across barriers (the
//    baseline's 2x syncthreads forced a vmcnt(0) drain every step).
//  - slot-permuted LDS (HW-verified in R2/R3): 16-row x 4-chunk(16B)
//    sub-blocks, slot(r,q) = r*4 + ((q+(r>>1))&3); linear DMA dest,
//    permutation encoded in the SOURCE address; fragment ds_read_b128
//    conflict-free (baseline: 6.55M conflicts/dispatch).
//  - s_setprio(1) around the 16-MFMA cluster.
//  - XCD-aware bijective block remap (grids are multiples of 8).
// MODE 0: scatter epilogue to Q (scaled 0.125*log2e) / K / V^T tiled,
//   2 per-64-col-chunk passes staged in the (free) LDS (R3-verified
//   layouts resized to 128 rows). MODE 1: fp32 direct out.
// =====================================================================
#define BAR8() do { asm volatile("" ::: "memory"); \
                    __builtin_amdgcn_s_barrier();  \
                    asm volatile("" ::: "memory"); } while (0)
#define VMC4()  asm volatile("s_waitcnt vmcnt(4)" ::: "memory")
#define VMC0()  asm volatile("s_waitcnt vmcnt(0)" ::: "memory")

template <int MODE>
__launch_bounds__(256, 3)
__global__ void gemm_tb(const ushort* __restrict__ A, const ushort* __restrict__ Bt,
                        const float* __restrict__ bias,
                        ushort* __restrict__ o0, ushort* __restrict__ o1,
                        ushort* __restrict__ o2, float* __restrict__ of,
                        int M, int N, int K) {
  __shared__ ushort smem[24576];  // 48 KiB: A bufs [0,12288), B bufs [12288,24576)
  const int NT = K >> 5;
  const int tid = threadIdx.x;
  const int wid = tid >> 6;
  const int lane = tid & 63;
  const int quad = lane >> 4;
  const int l16 = lane & 15;
  const int wm = (wid >> 1) * 64;
  const int wn = (wid & 1) * 64;

  // XCD-aware bijective remap (gridDim.x*gridDim.y % 8 == 0 in both modes)
  int wg = blockIdx.y * gridDim.x + blockIdx.x;
  const int ntx = gridDim.x;
  const int cpx = (ntx * gridDim.y) >> 3;
  wg = (wg & 7) * cpx + (wg >> 3);
  const int m0 = (wg / ntx) * 128;
  const int n0 = (wg % ntx) * 128;

  // ---- staging addressing (slot-permuted source, linear dest) ----
  const int r_l = lane >> 2;                      // row within 16-row sub-block
  const int q_l = ((lane & 3) - (r_l >> 1)) & 3;  // logical k-chunk this lane sources
  // wave stages A rows wid*32..+31 and B rows wid*32..+31 (2 sub-blocks each)
  const ushort* gA0 = A + (size_t)(m0 + wid * 32 + r_l) * K + q_l * 8;
  const ushort* gB0 = Bt + (size_t)(n0 + wid * 32 + r_l) * K + q_l * 8;
  ushort* dA0 = smem + wid * 1024 + lane * 8;
  ushort* dB0 = smem + 12288 + wid * 1024 + lane * 8;

  auto stage = [&](int t, int bs) {   // 4 VMEM ops per thread
    const ushort* sa = gA0 + t * 32;
    ushort* da = dA0 + bs * 4096;
    glds16(sa, da);
    glds16(sa + 16 * K, da + 512);
    const ushort* sb = gB0 + t * 32;
    ushort* db = dB0 + bs * 4096;
    glds16(sb, db);
    glds16(sb + 16 * K, db + 512);
  };

  // ---- fragment read addressing ----
  const int slot8 = (l16 * 4 + ((quad + (l16 >> 1)) & 3)) * 8;
  const int abase = (wm >> 4) * 512 + slot8;            // + b*4096
  const int bbase = 12288 + (wn >> 4) * 512 + slot8;    // + b*4096

  f32x4 acc[4][4];
#pragma unroll
  for (int i = 0; i < 4; ++i)
#pragma unroll
    for (int j = 0; j < 4; ++j) acc[i][j] = (f32x4){0.f, 0.f, 0.f, 0.f};

  // ---- prologue: 2-deep prefetch ----
  stage(0, 0);
  stage(1, 1);
  VMC4();   // tile 0 landed; tile 1 (4 ops) may remain in flight
  BAR8();

  int b = 0;
  for (int t = 0; t < NT; ++t) {
    bf16x8 af[4], bfr[4];
    const int boff = b * 4096;
#pragma unroll
    for (int i = 0; i < 4; ++i)
      af[i] = *(const bf16x8*)(smem + boff + abase + i * 512);
#pragma unroll
    for (int j = 0; j < 4; ++j)
      bfr[j] = *(const bf16x8*)(smem + boff + bbase + j * 512);
    const int b2 = (b == 0) ? 2 : b - 1;    // (t+2) % 3
    if (t + 2 < NT) stage(t + 2, b2);       // overwrites buf read at t-1 (safe post-bar)
    __builtin_amdgcn_s_setprio(1);
#pragma unroll
    for (int i = 0; i < 4; ++i)
#pragma unroll
      for (int j = 0; j < 4; ++j)
        acc[i][j] = __builtin_amdgcn_mfma_f32_16x16x32_bf16(af[i], bfr[j], acc[i][j], 0, 0, 0);
    __builtin_amdgcn_s_setprio(0);
    // counted wait: buf for t+1 (staged at t-1) must be complete; the 4 ops
    // of stage(t+2) issued THIS iter may remain in flight. Never a mid-loop
    // full drain except at the tail.
    if (t + 2 < NT) { VMC4(); } else if (t + 1 < NT) { VMC0(); }
    BAR8();
    b = (b == 2) ? 0 : b + 1;
  }

  if (MODE == 1) {
#pragma unroll
    for (int i = 0; i < 4; ++i)
#pragma unroll
      for (int j = 0; j < 4; ++j) {
        const int col = n0 + wn + j * 16 + l16;
        const float bv = bias[col];
#pragma unroll
        for (int r = 0; r < 4; ++r) {
          const int row = m0 + wm + i * 16 + quad * 4 + r;
          of[(size_t)row * N + col] = acc[i][j][r] + bv;
        }
      }
  } else {
    // ---- scatter epilogue: 2 per-64-col-chunk passes, staged in LDS ----
    const int bb = m0 >> 11;
    const int s0 = m0 & 2047;
    const int wr = wid >> 1;     // row-half owner (R base = wr*64)
    const int wcol = wid & 1;    // col-half owner
#pragma unroll
    for (int hc = 0; hc < 2; ++hc) {
      const int gc0 = n0 + hc * 64;
      const int sel = gc0 >> 10;              // 0=Q 1=K 2=V (chunk head-aligned)
      const int head = (gc0 & 1023) >> 6;
      const size_t bh = (size_t)(bb * 16 + head);
      __syncthreads();                        // K-loop / prior pass reads done
      if (wcol == hc) {
#pragma unroll
        for (int j = 0; j < 4; ++j) {
          const int dloc = j * 16 + l16;      // 0..63
          const float bv = bias[gc0 + dloc];
#pragma unroll
          for (int i = 0; i < 4; ++i) {
#pragma unroll
            for (int r = 0; r < 4; ++r) {
              const int R = wr * 64 + i * 16 + quad * 4 + r;   // 0..127
              float v = acc[i][j][r] + bv;
              if (sel == 0) v *= 0.18033688011112042f;  // (1/8)*log2(e)
              const ushort u = f2bf(v);
              if (sel == 2) {
                const int lc = R >> 3;        // s-chunk 0..15
                smem[dloc * 128 + ((lc ^ (dloc & 7)) << 3) + (R & 7)] = u;
              } else {
                smem[R * 64 + (((dloc >> 3) ^ (R & 7)) << 3) + (dloc & 7)] = u;
              }
            }
          }
        }
      }
      __syncthreads();
      if (sel != 2) {
        ushort* o = sel ? o1 : o0;
        const int R = tid >> 1;               // 0..127
        const int gh = tid & 1;               // 64B half of the row
        ushort* dst = o + (bh * 2048 + s0 + R) * 64 + gh * 32;
        const int key = R & 7;
        const uint4* srow = (const uint4*)(smem + R * 64);
#pragma unroll
        for (int g = 0; g < 4; ++g)
          ((uint4*)dst)[g] = srow[(gh * 4 + g) ^ key];
      } else {
        const int d = tid >> 2;               // 0..63
        const int sq = tid & 3;               // 32-s quarter
        ushort* dst = o2 + (((size_t)(bh * 32 + (s0 >> 6) + (sq >> 1))) << 12) +
                      d * 64 + (sq & 1) * 32;
        const uint4* srow = (const uint4*)(smem + d * 128);
#pragma unroll
        for (int g = 0; g < 4; ++g)
          ((uint4*)dst)[g] = srow[(sq * 4 + g) ^ (d & 7)];
      }
    }
  }
}

// ---------------- flash attention (causal) ----------------
// + s_setprio around MFMA clusters (m191: attn-applicable — waves diverge)
// + XCD remap: all 8 pair-blocks of one (b,h) on one XCD; 8 bh x 512KB K/V
//   = exactly one 4MB L2.
__launch_bounds__(256)
__global__ void attn_fused(const ushort* __restrict__ Qb, const ushort* __restrict__ Kb,
                           const ushort* __restrict__ Vt, ushort* __restrict__ Ob) {
  int wg0 = blockIdx.y * 8 + blockIdx.x;
  const int w = (wg0 & 7) * 64 + (wg0 >> 3);  // bijective over 512
  const int bh = w >> 3;           // b*16 + h
  const int pair = w & 7;          // 0..7
  const int tid = threadIdx.x;
  const int wid = tid >> 6;
  const int lane = tid & 63;
  const int quad = lane >> 4;
  const int l16 = lane & 15;

  __shared__ ushort Ks[2][2][64 * 32];
  __shared__ ushort Vs[2][2][64 * 32];

  const int lr = lane >> 2;
  const int jphys = lane & 3;
  const int skey = (lr >> 1) & 3;
  const int jlog = jphys ^ skey;
  const int srow = wid * 16 + lr;
  const ushort* KgL = Kb + (size_t)bh * 2048 * 64 + (size_t)srow * 64 + jlog * 8;
  const ushort* VgL = Vt + (size_t)bh * 32 * 4096 + (size_t)srow * 64 + jlog * 8;
  ushort* ldsK0[2], *ldsK1[2], *ldsV0[2], *ldsV1[2];
#pragma unroll
  for (int buf = 0; buf < 2; ++buf) {
    ldsK0[buf] = &Ks[buf][0][wid * 16 * 32] + lane * 8;
    ldsK1[buf] = &Ks[buf][1][wid * 16 * 32] + lane * 8;
    ldsV0[buf] = &Vs[buf][0][wid * 16 * 32] + lane * 8;
    ldsV1[buf] = &Vs[buf][1][wid * 16 * 32] + lane * 8;
  }
  auto stage = [&](int jt) {
    const int buf = jt & 1;
    const ushort* ks = KgL + (size_t)jt * 4096;
    const ushort* vs = VgL + (size_t)jt * 4096;
    glds16(ks, ldsK0[buf]);
    glds16(ks + 32, ldsK1[buf]);
    glds16(vs, ldsV0[buf]);
    glds16(vs + 32, ldsV1[buf]);
  };

  const int rkey = (l16 >> 1) & 3;
  const int b = bh >> 4, h = bh & 15;

  auto process = [&](int qt) {
    const int qg0 = qt * 128 + wid * 32;

    const ushort* Qg = Qb + ((size_t)bh * 2048 + qg0) * 64;
    bf16x8 qa[2][2];
#pragma unroll
    for (int f = 0; f < 2; ++f)
#pragma unroll
      for (int hh = 0; hh < 2; ++hh)
        qa[f][hh] = *(const bf16x8*)(Qg + (f * 16 + l16) * 64 + hh * 32 + quad * 8);

    f32x4 o[2][4];
    float rs[2];
#pragma unroll
    for (int f = 0; f < 2; ++f) {
      rs[f] = 0.f;
#pragma unroll
      for (int m = 0; m < 4; ++m) o[f][m] = (f32x4){0.f, 0.f, 0.f, 0.f};
    }

    const int nIt = 2 * qt + 2;
    stage(0);

    for (int jt = 0; jt < nIt; ++jt) {
      __syncthreads();
      if (jt + 1 < nIt) stage(jt + 1);

      const int kvb = jt * 64;
      if (kvb > qg0 + 31) continue;
      const int buf = jt & 1;

      f32x4 s[2][4];
      __builtin_amdgcn_s_setprio(1);
#pragma unroll
      for (int n = 0; n < 4; ++n) {
        const int koff = (n * 16 + l16) * 32 + (quad ^ rkey) * 8;
        bf16x8 kb0 = *(const bf16x8*)&Ks[buf][0][koff];
        bf16x8 kb1 = *(const bf16x8*)&Ks[buf][1][koff];
#pragma unroll
        for (int f = 0; f < 2; ++f) {
          f32x4 z = (f32x4){0.f, 0.f, 0.f, 0.f};
          z = __builtin_amdgcn_mfma_f32_16x16x32_bf16(kb0, qa[f][0], z, 0, 0, 0);
          z = __builtin_amdgcn_mfma_f32_16x16x32_bf16(kb1, qa[f][1], z, 0, 0, 0);
          s[f][n] = z;
        }
      }
      __builtin_amdgcn_s_setprio(0);

      bf16x4 p[2][4];
      if (kvb + 63 <= qg0) {
#pragma unroll
        for (int f = 0; f < 2; ++f)
#pragma unroll
          for (int n = 0; n < 4; ++n) {
            float pe[4];
#pragma unroll
            for (int r = 0; r < 4; ++r) {
              pe[r] = fast_exp2(s[f][n][r]);
              rs[f] += pe[r];
            }
            p[f][n] = (bf16x4){(__bf16)pe[0], (__bf16)pe[1], (__bf16)pe[2], (__bf16)pe[3]};
          }
      } else {
#pragma unroll
        for (int f = 0; f < 2; ++f) {
          const int qg = qg0 + f * 16 + l16;
#pragma unroll
          for (int n = 0; n < 4; ++n) {
            const int kg0 = kvb + n * 16 + quad * 4;
            float pe[4];
#pragma unroll
            for (int r = 0; r < 4; ++r) {
              float e = fast_exp2(s[f][n][r]);
              pe[r] = (kg0 + r > qg) ? 0.f : e;
              rs[f] += pe[r];
            }
            p[f][n] = (bf16x4){(__bf16)pe[0], (__bf16)pe[1], (__bf16)pe[2], (__bf16)pe[3]};
          }
        }
      }

      __builtin_amdgcn_s_setprio(1);
#pragma unroll
      for (int m = 0; m < 4; ++m) {
        const int vrow = (m * 16 + l16) * 32;
#pragma unroll
        for (int n = 0; n < 4; ++n) {
          const int clog = (n & 1) * 2 + (quad >> 1);
          const int voff = vrow + (clog ^ rkey) * 8 + (quad & 1) * 4;
          bf16x4 va = *(const bf16x4*)&Vs[buf][n >> 1][voff];
#pragma unroll
          for (int f = 0; f < 2; ++f) o[f][m] = mfma16(va, p[f][n], o[f][m]);
        }
      }
      __builtin_amdgcn_s_setprio(0);
    }

#pragma unroll
    for (int f = 0; f < 2; ++f) {
      float t = rs[f];
      t += __shfl_xor(t, 16, 64);
      t += __shfl_xor(t, 32, 64);
      const float il = 1.f / t;
      const int q = qg0 + f * 16 + l16;
      ushort* dst = Ob + ((size_t)b * 2048 + q) * 1024 + h * 64;
#pragma unroll
      for (int m = 0; m < 4; ++m) {
        ushort4 w2;
        w2.x = f2bf(o[f][m][0] * il);
        w2.y = f2bf(o[f][m][1] * il);
        w2.z = f2bf(o[f][m][2] * il);
        w2.w = f2bf(o[f][m][3] * il);
        *(ushort4*)(dst + m * 16 + quad * 4) = w2;
      }
    }
  };

  process(15 - pair);
  __syncthreads();
  process(pair);
}

// ---------------- launch ----------------
extern "C" void kernel_launch(void* const* d_in, const int* in_sizes, int n_in,
                              void* d_out, int out_size, void* d_ws, size_t ws_size,
                              hipStream_t stream) {
  const float* x    = (const float*)d_in[0];  // [4,2048,1024]
  const float* Wqkv = (const float*)d_in[1];  // [1024,3072]
  const float* bqkv = (const float*)d_in[2];  // [3072]
  const float* Wo   = (const float*)d_in[3];  // [1024,1024]
  const float* bo   = (const float*)d_in[4];  // [1024]
  float* out = (float*)d_out;                 // [4,2048,1024] fp32

  char* ws = (char*)d_ws;
  size_t off = 0;
  auto alloc = [&](size_t bytes) {
    void* p = ws + off;
    off += (bytes + 255) & ~(size_t)255;
    return p;
  };
  ushort* xbf    = (ushort*)alloc((size_t)8192 * 1024 * 2);
  ushort* Wqkv_t = (ushort*)alloc((size_t)3072 * 1024 * 2);
  ushort* Wo_t   = (ushort*)alloc((size_t)1024 * 1024 * 2);
  ushort* Qb     = (ushort*)alloc((size_t)64 * 2048 * 64 * 2);
  ushort* Kb     = (ushort*)alloc((size_t)64 * 2048 * 64 * 2);
  ushort* Vb     = (ushort*)alloc((size_t)64 * 2048 * 64 * 2);  // tiled V^T
  ushort* Ab     = (ushort*)alloc((size_t)8192 * 1024 * 2);

  // 1. x -> bf16
  conv_bf16<<<dim3(8192), dim3(256), 0, stream>>>((const float4*)x, (ushort4*)xbf,
                                                  8192 * 1024 / 4);
  // 2. transpose weights -> bf16 [N][K]
  transpose_f32_bf16<<<dim3(96, 32), dim3(32, 8), 0, stream>>>(Wqkv, Wqkv_t, 1024, 3072);
  transpose_f32_bf16<<<dim3(32, 32), dim3(32, 8), 0, stream>>>(Wo, Wo_t, 1024, 1024);
  // 3. QKV projection: triple-buffered counted-vmcnt GEMM, scatter epilogue
  gemm_tb<0><<<dim3(24, 64), dim3(256), 0, stream>>>(xbf, Wqkv_t, bqkv, Qb, Kb, Vb, nullptr,
                                                     8192, 3072, 1024);
  // 4. causal flash attention (paired q-tiles; bh-per-XCD remap)
  attn_fused<<<dim3(8, 64), dim3(256), 0, stream>>>(Qb, Kb, Vb, Ab);
  // 5. output projection (same triple-buffered template, fp32 out)
  gemm_tb<1><<<dim3(8, 64), dim3(256), 0, stream>>>(Ab, Wo_t, bo, nullptr, nullptr, nullptr,
                                                    out, 8192, 1024, 1024);
}